// Round 12
// baseline (1215.986 us; speedup 1.0000x reference)
//
#include <hip/hip_runtime.h>
#include <hip/hip_bf16.h>
#include <math.h>

typedef unsigned short u16;
typedef __attribute__((ext_vector_type(8))) short short8;
typedef __attribute__((ext_vector_type(4))) short short4v;
typedef __attribute__((ext_vector_type(4))) float floatx4;

__device__ __forceinline__ float bf2f(u16 u) {
  union { float f; unsigned u; } v; v.u = ((unsigned)u) << 16; return v.f;
}
__device__ __forceinline__ u16 f2bf(float f) {
  union { float f; unsigned u; } v; v.f = f;
  unsigned r = (v.u + 0x7FFFu + ((v.u >> 16) & 1u)) >> 16;
  return (u16)r;
}
__device__ __forceinline__ float sigm(float x) {
  return __builtin_amdgcn_rcpf(1.0f + __expf(-x));
}
__device__ __forceinline__ float ftanh(float x) {
  return 1.0f - 2.0f * __builtin_amdgcn_rcpf(1.0f + __expf(2.0f * x));
}

// async global->LDS, 16B/lane; LDS dest = wave-uniform base + lane*16
__device__ __forceinline__ void ld_g2l16(const u16* g, u16* l) {
  __builtin_amdgcn_global_load_lds(
      (const __attribute__((address_space(1))) void*)g,
      (__attribute__((address_space(3))) void*)l, 16, 0, 0);
}

// R4/R7-measured-best grid order: per XCD, by fastest within a disjoint strip.
__device__ __forceinline__ void swz(int blk, int NX, int NY, int& bx, int& by) {
  if ((NY & 7) == 0) {
    const int strip = NY >> 3;
    const int xcd = blk & 7;
    const int q = blk >> 3;
    bx = q / strip;
    by = xcd * strip + (q - bx * strip);
  } else {
    bx = blk % NX;
    by = blk / NX;
  }
}

#define BM 128
#define BN 128
#define BK 64    // 32 K-iters at K=2048: fewest barrier drains (R5-vs-R6 measured win)
                 // LDS row = 128B = 8x16B chunks; XOR chunk^(row&7) -> conflict-free (R5: 0)

#define MODE_ZR   1
#define MODE_OUT  2

// ---------------- Leaf: h = (1 - sigm(word@Wz + bz)) * tanh(word@Wh + bh)
__global__ __launch_bounds__(256) void leaf_fused(
    const u16* __restrict__ word, const u16* __restrict__ BLT,
    const float* __restrict__ bz, const float* __restrict__ bh,
    u16* __restrict__ hout)   // 32768 x 1024 bf16
{
  __shared__ u16 sA [BM * BK];
  __shared__ u16 sBz[BN * BK];
  __shared__ u16 sBh[BN * BK];
  const int tid  = threadIdx.x;
  int bx, by; swz(blockIdx.x, 8, 256, bx, by);
  const int m0   = by * BM;
  const int n0   = bx * BN;
  const int lane = tid & 63;
  const int wave = tid >> 6;
  const int wm   = (wave >> 1) * 64;
  const int wn   = (wave & 1) * 64;
  const int lr   = lane & 15;
  const int q4   = lane >> 4;
  const int qd   = q4 * 4;
  const int xs   = lr & 7;
  const int srow = lane >> 3;
  const int sc   = lane & 7;
  const int goff = (sc ^ srow) * 8;

  const u16* aP [4]; const u16* bzP[4]; const u16* bhP[4];
  #pragma unroll
  for (int t = 0; t < 4; ++t) {
    const int row = (wave * 4 + t) * 8 + srow;
    aP [t] = word + (size_t)(m0 + row) * 512 + goff;
    bzP[t] = BLT  + (size_t)(n0 + row) * 512 + goff;
    bhP[t] = BLT  + (size_t)(1024 + n0 + row) * 512 + goff;
  }

  floatx4 accz[4][4], acch[4][4];
  #pragma unroll
  for (int j = 0; j < 4; ++j)
    #pragma unroll
    for (int i = 0; i < 4; ++i) {
      accz[j][i] = (floatx4){0.f, 0.f, 0.f, 0.f};
      acch[j][i] = (floatx4){0.f, 0.f, 0.f, 0.f};
    }

  for (int kt = 0; kt < 512 / BK; ++kt) {
    #pragma unroll
    for (int t = 0; t < 4; ++t) {
      const int slab = wave * 4 + t;
      ld_g2l16(aP [t], &sA [slab * 512]);
      ld_g2l16(bzP[t], &sBz[slab * 512]);
      ld_g2l16(bhP[t], &sBh[slab * 512]);
      aP[t] += BK; bzP[t] += BK; bhP[t] += BK;
    }
    __syncthreads();
    #pragma unroll
    for (int s = 0; s < 2; ++s) {
      const int ck = ((s * 4 + q4) ^ xs) * 8;
      short8 af[4], bz8[4], bh8[4];
      #pragma unroll
      for (int i = 0; i < 4; ++i)
        af[i] = *(const short8*)(&sA[(wm + i * 16 + lr) * BK + ck]);
      #pragma unroll
      for (int j = 0; j < 4; ++j) {
        bz8[j] = *(const short8*)(&sBz[(wn + j * 16 + lr) * BK + ck]);
        bh8[j] = *(const short8*)(&sBh[(wn + j * 16 + lr) * BK + ck]);
      }
      #pragma unroll
      for (int j = 0; j < 4; ++j)
        #pragma unroll
        for (int i = 0; i < 4; ++i) {
          accz[j][i] = __builtin_amdgcn_mfma_f32_16x16x32_bf16(bz8[j], af[i], accz[j][i], 0, 0, 0);
          acch[j][i] = __builtin_amdgcn_mfma_f32_16x16x32_bf16(bh8[j], af[i], acch[j][i], 0, 0, 0);
        }
    }
    __syncthreads();
  }

  #pragma unroll
  for (int j = 0; j < 4; ++j) {
    const int cb = n0 + wn + j * 16 + qd;
    const float4 bz4 = *(const float4*)(bz + cb);
    const float4 bh4 = *(const float4*)(bh + cb);
    #pragma unroll
    for (int i = 0; i < 4; ++i) {
      const int grow = m0 + wm + i * 16 + lr;
      short4v o;
      #pragma unroll
      for (int r = 0; r < 4; ++r) {
        const float z  = sigm(accz[j][i][r] + ((const float*)&bz4)[r]);
        const float ht = ftanh(acch[j][i][r] + ((const float*)&bh4)[r]);
        o[r] = (short)f2bf((1.f - z) * ht);
      }
      *(short4v*)(hout + (size_t)grow * 1024 + cb) = o;
    }
  }
}

// ---------------- Big-level GEMM (levels 0-2): C = A @ BT^T, fused epilogues.
__global__ __launch_bounds__(256) void gemm_fused(
    const u16* __restrict__ A, const u16* __restrict__ BT,
    int M, int K, int NX, int NY, int mode,
    const float* __restrict__ bias_z, const float* __restrict__ bias_r,
    const float* __restrict__ bias_h,
    const u16* __restrict__ hin2, const u16* __restrict__ zin,
    u16* __restrict__ out0, u16* __restrict__ out1, float* __restrict__ outf)
{
  __shared__ u16 sA[BM * BK];
  __shared__ u16 sB[BN * BK];
  const int tid  = threadIdx.x;
  int bx, by; swz(blockIdx.x, NX, NY, bx, by);
  const int m0   = by * BM;
  const int n0   = bx * BN;
  const int lane = tid & 63;
  const int wave = tid >> 6;
  const int wm   = (wave >> 1) * 64;
  const int wn   = (wave & 1) * 64;
  const int lr   = lane & 15;
  const int q4   = lane >> 4;
  const int qd   = q4 * 4;
  const int xs   = lr & 7;
  const int srow = lane >> 3;
  const int sc   = lane & 7;
  const int goff = (sc ^ srow) * 8;

  const u16* aP[4]; const u16* bP[4];
  #pragma unroll
  for (int t = 0; t < 4; ++t) {
    const int row = (wave * 4 + t) * 8 + srow;
    aP[t] = A  + (size_t)(m0 + row) * K + goff;
    bP[t] = BT + (size_t)(n0 + row) * K + goff;
  }

  floatx4 acc[4][4];
  #pragma unroll
  for (int j = 0; j < 4; ++j)
    #pragma unroll
    for (int i = 0; i < 4; ++i)
      acc[j][i] = (floatx4){0.f, 0.f, 0.f, 0.f};

  const int ksteps = K / BK;
  for (int kt = 0; kt < ksteps; ++kt) {
    #pragma unroll
    for (int t = 0; t < 4; ++t) {
      const int slab = wave * 4 + t;
      ld_g2l16(aP[t], &sA[slab * 512]);
      ld_g2l16(bP[t], &sB[slab * 512]);
      aP[t] += BK; bP[t] += BK;
    }
    __syncthreads();
    #pragma unroll
    for (int s = 0; s < 2; ++s) {
      const int ck = ((s * 4 + q4) ^ xs) * 8;
      short8 af[4], bfr[4];
      #pragma unroll
      for (int i = 0; i < 4; ++i)
        af[i] = *(const short8*)(&sA[(wm + i * 16 + lr) * BK + ck]);
      #pragma unroll
      for (int j = 0; j < 4; ++j)
        bfr[j] = *(const short8*)(&sB[(wn + j * 16 + lr) * BK + ck]);
      #pragma unroll
      for (int j = 0; j < 4; ++j)
        #pragma unroll
        for (int i = 0; i < 4; ++i)
          acc[j][i] = __builtin_amdgcn_mfma_f32_16x16x32_bf16(bfr[j], af[i], acc[j][i], 0, 0, 0);
    }
    __syncthreads();
  }

  #pragma unroll
  for (int j = 0; j < 4; ++j) {
    const int cb = n0 + wn + j * 16 + qd;
    if (mode == MODE_ZR) {
      if (cb < 1024) {
        const float4 b4 = *(const float4*)(bias_z + cb);
        #pragma unroll
        for (int i = 0; i < 4; ++i) {
          const int grow = m0 + wm + i * 16 + lr;
          if (grow >= M) continue;
          short4v o;
          #pragma unroll
          for (int r = 0; r < 4; ++r)
            o[r] = (short)f2bf(sigm(acc[j][i][r] + ((const float*)&b4)[r]));
          *(short4v*)(out0 + (size_t)grow * 1024 + cb) = o;
        }
      } else {
        const int c2 = cb - 1024;
        const float4 b4 = *(const float4*)(bias_r + c2);
        #pragma unroll
        for (int i = 0; i < 4; ++i) {
          const int grow = m0 + wm + i * 16 + lr;
          if (grow >= M) continue;
          const short4v hl4 = *(const short4v*)(hin2 + (size_t)grow * 2048 + c2);
          const short4v hr4 = *(const short4v*)(hin2 + (size_t)grow * 2048 + 1024 + c2);
          short4v ol, orr;
          #pragma unroll
          for (int r = 0; r < 4; ++r) {
            const float rv = sigm(acc[j][i][r] + ((const float*)&b4)[r]);
            ol[r]  = (short)f2bf(rv * bf2f((u16)hl4[r]));
            orr[r] = (short)f2bf(rv * bf2f((u16)hr4[r]));
          }
          *(short4v*)(out1 + (size_t)grow * 2048 + c2)        = ol;
          *(short4v*)(out1 + (size_t)grow * 2048 + 1024 + c2) = orr;
        }
      }
    } else { // MODE_OUT
      const float4 b4 = *(const float4*)(bias_h + cb);
      #pragma unroll
      for (int i = 0; i < 4; ++i) {
        const int grow = m0 + wm + i * 16 + lr;
        if (grow >= M) continue;
        const short4v z4  = *(const short4v*)(zin  + (size_t)grow * 1024 + cb);
        const short4v hl4 = *(const short4v*)(hin2 + (size_t)grow * 2048 + cb);
        const short4v hr4 = *(const short4v*)(hin2 + (size_t)grow * 2048 + 1024 + cb);
        float h[4];
        #pragma unroll
        for (int r = 0; r < 4; ++r) {
          const float ht = ftanh(acc[j][i][r] + ((const float*)&b4)[r]);
          const float z  = bf2f((u16)z4[r]);
          h[r] = z * (bf2f((u16)hl4[r]) + bf2f((u16)hr4[r])) + (1.f - z) * ht;
        }
        if (outf) {
          *(float4*)(outf + (size_t)grow * 1024 + cb) = (float4){h[0], h[1], h[2], h[3]};
        } else {
          short4v o;
          #pragma unroll
          for (int r = 0; r < 4; ++r) o[r] = (short)f2bf(h[r]);
          *(short4v*)(out0 + (size_t)grow * 1024 + cb) = o;
        }
      }
    }
  }
}

// ---------------- Split-K phase 1 (levels 3-8): bf16 partials, plain stores.
__global__ __launch_bounds__(256) void gemm_pk(
    const u16* __restrict__ A, const u16* __restrict__ BT,
    int K, int TX, int S, int Mr,
    u16* __restrict__ pbuf)
{
  __shared__ u16 sA[BM * BK];
  __shared__ u16 sB[BN * BK];
  const int tid  = threadIdx.x;
  const int blk  = blockIdx.x;
  const int sp   = blk % S;
  const int tile = blk / S;
  const int bx   = tile % TX;
  const int by   = tile / TX;
  const int N    = TX * 128;
  const int m0   = by * BM;
  const int n0   = bx * BN;
  const int k0   = sp * (K / S);
  const int lane = tid & 63;
  const int wave = tid >> 6;
  const int wm   = (wave >> 1) * 64;
  const int wn   = (wave & 1) * 64;
  const int lr   = lane & 15;
  const int q4   = lane >> 4;
  const int qd   = q4 * 4;
  const int xs   = lr & 7;
  const int srow = lane >> 3;
  const int sc   = lane & 7;
  const int goff = (sc ^ srow) * 8;

  const u16* aP[4]; const u16* bP[4];
  #pragma unroll
  for (int t = 0; t < 4; ++t) {
    const int row = (wave * 4 + t) * 8 + srow;
    aP[t] = A  + (size_t)(m0 + row) * K + k0 + goff;  // OOB rows: in-ws garbage, masked in reduce
    bP[t] = BT + (size_t)(n0 + row) * K + k0 + goff;
  }

  floatx4 acc[4][4];
  #pragma unroll
  for (int j = 0; j < 4; ++j)
    #pragma unroll
    for (int i = 0; i < 4; ++i)
      acc[j][i] = (floatx4){0.f, 0.f, 0.f, 0.f};

  const int ksteps = (K / S) / BK;
  for (int kt = 0; kt < ksteps; ++kt) {
    #pragma unroll
    for (int t = 0; t < 4; ++t) {
      const int slab = wave * 4 + t;
      ld_g2l16(aP[t], &sA[slab * 512]);
      ld_g2l16(bP[t], &sB[slab * 512]);
      aP[t] += BK; bP[t] += BK;
    }
    __syncthreads();
    #pragma unroll
    for (int s = 0; s < 2; ++s) {
      const int ck = ((s * 4 + q4) ^ xs) * 8;
      short8 af[4], bfr[4];
      #pragma unroll
      for (int i = 0; i < 4; ++i)
        af[i] = *(const short8*)(&sA[(wm + i * 16 + lr) * BK + ck]);
      #pragma unroll
      for (int j = 0; j < 4; ++j)
        bfr[j] = *(const short8*)(&sB[(wn + j * 16 + lr) * BK + ck]);
      #pragma unroll
      for (int j = 0; j < 4; ++j)
        #pragma unroll
        for (int i = 0; i < 4; ++i)
          acc[j][i] = __builtin_amdgcn_mfma_f32_16x16x32_bf16(bfr[j], af[i], acc[j][i], 0, 0, 0);
    }
    __syncthreads();
  }

  u16* base = pbuf + (size_t)sp * Mr * N;
  #pragma unroll
  for (int j = 0; j < 4; ++j) {
    const int cb = n0 + wn + j * 16 + qd;
    #pragma unroll
    for (int i = 0; i < 4; ++i) {
      const int grow = m0 + wm + i * 16 + lr;
      short4v o;
      #pragma unroll
      for (int r = 0; r < 4; ++r) o[r] = (short)f2bf(acc[j][i][r]);
      *(short4v*)(base + (size_t)grow * N + cb) = o;
    }
  }
}

// ---------------- Split-K phase 2: sum S bf16 slices + ZR epilogue (N=2048)
__global__ __launch_bounds__(256) void reduce_zr(
    const u16* __restrict__ pbuf, int M, int Mr, int S,
    const float* __restrict__ bias_z, const float* __restrict__ bias_r,
    const u16* __restrict__ hin2,
    u16* __restrict__ out0, u16* __restrict__ out1)
{
  const int t = blockIdx.x * 256 + threadIdx.x;
  const int grow = t >> 9;
  const int cb = (t & 511) * 4;
  if (grow >= M) return;
  float v[4] = {0.f, 0.f, 0.f, 0.f};
  for (int s = 0; s < S; ++s) {
    const short4v p = *(const short4v*)(pbuf + ((size_t)s * Mr + grow) * 2048 + cb);
    #pragma unroll
    for (int r = 0; r < 4; ++r) v[r] += bf2f((u16)p[r]);
  }
  if (cb < 1024) {
    short4v o;
    #pragma unroll
    for (int r = 0; r < 4; ++r)
      o[r] = (short)f2bf(sigm(v[r] + bias_z[cb + r]));
    *(short4v*)(out0 + (size_t)grow * 1024 + cb) = o;
  } else {
    const int c2 = cb - 1024;
    const short4v hl4 = *(const short4v*)(hin2 + (size_t)grow * 2048 + c2);
    const short4v hr4 = *(const short4v*)(hin2 + (size_t)grow * 2048 + 1024 + c2);
    short4v ol, orr;
    #pragma unroll
    for (int r = 0; r < 4; ++r) {
      const float rv = sigm(v[r] + bias_r[c2 + r]);
      ol[r]  = (short)f2bf(rv * bf2f((u16)hl4[r]));
      orr[r] = (short)f2bf(rv * bf2f((u16)hr4[r]));
    }
    *(short4v*)(out1 + (size_t)grow * 2048 + c2)        = ol;
    *(short4v*)(out1 + (size_t)grow * 2048 + 1024 + c2) = orr;
  }
}

// ---------------- Split-K phase 2: sum S bf16 slices + OUT epilogue (N=1024)
__global__ __launch_bounds__(256) void reduce_out(
    const u16* __restrict__ pbuf, int M, int Mr, int S,
    const float* __restrict__ bias_h,
    const u16* __restrict__ hin2, const u16* __restrict__ zin,
    u16* __restrict__ out0, float* __restrict__ outf)
{
  const int t = blockIdx.x * 256 + threadIdx.x;
  const int grow = t >> 8;
  const int cb = (t & 255) * 4;
  if (grow >= M) return;
  float v[4] = {0.f, 0.f, 0.f, 0.f};
  for (int s = 0; s < S; ++s) {
    const short4v p = *(const short4v*)(pbuf + ((size_t)s * Mr + grow) * 1024 + cb);
    #pragma unroll
    for (int r = 0; r < 4; ++r) v[r] += bf2f((u16)p[r]);
  }
  const short4v z4  = *(const short4v*)(zin  + (size_t)grow * 1024 + cb);
  const short4v hl4 = *(const short4v*)(hin2 + (size_t)grow * 2048 + cb);
  const short4v hr4 = *(const short4v*)(hin2 + (size_t)grow * 2048 + 1024 + cb);
  float h[4];
  #pragma unroll
  for (int r = 0; r < 4; ++r) {
    const float ht = ftanh(v[r] + bias_h[cb + r]);
    const float z  = bf2f((u16)z4[r]);
    h[r] = z * (bf2f((u16)hl4[r]) + bf2f((u16)hr4[r])) + (1.f - z) * ht;
  }
  if (outf) {
    *(float4*)(outf + (size_t)grow * 1024 + cb) = (float4){h[0], h[1], h[2], h[3]};
  } else {
    short4v o;
    #pragma unroll
    for (int r = 0; r < 4; ++r) o[r] = (short)f2bf(h[r]);
    *(short4v*)(out0 + (size_t)grow * 1024 + cb) = o;
  }
}

// ---------------- prep mega-kernel: token gather + LDS-transposed weight packs
// Segments by blockIdx: [0,8192) gather; [8192,9216) B1T; [9216,9728) B2T;
// [9728,9984) BLT; [9984,9988) biases. All pack reads/writes coalesced via
// 64x64 LDS transpose tile (+1 pad); fixes old pack_all's 16x line over-fetch.
__global__ __launch_bounds__(256) void prep_all(
    const int* __restrict__ tokens, const float* __restrict__ emb,
    const float* __restrict__ Uzl, const float* __restrict__ Uzr,
    const float* __restrict__ Url, const float* __restrict__ Urr,
    const float* __restrict__ Uhl, const float* __restrict__ Uhr,
    const float* __restrict__ Wz,  const float* __restrict__ Wh,
    const float* bz0, const float* bz1, const float* bz2,
    const float* br0, const float* br1, const float* br2,
    const float* bh0, const float* bh1, const float* bh2,
    u16* __restrict__ word,
    u16* __restrict__ B1T, u16* __restrict__ B2T, u16* __restrict__ BLT,
    float* __restrict__ bz, float* __restrict__ br, float* __restrict__ bh)
{
  __shared__ float sT[64][65];
  const int tid = threadIdx.x;
  int b = blockIdx.x;

  if (b < 8192) {                       // token gather (f32 -> bf16)
    const int t = b * 256 + tid;
    const int row = t >> 6;
    const int col = (t & 63) * 8;
    const float* src = emb + (size_t)tokens[row] * 512 + col;
    float4 a = *(const float4*)src;
    float4 c = *(const float4*)(src + 4);
    short8 v;
    v[0] = (short)f2bf(a.x); v[1] = (short)f2bf(a.y);
    v[2] = (short)f2bf(a.z); v[3] = (short)f2bf(a.w);
    v[4] = (short)f2bf(c.x); v[5] = (short)f2bf(c.y);
    v[6] = (short)f2bf(c.z); v[7] = (short)f2bf(c.w);
    *(short8*)(word + (size_t)row * 512 + col) = v;
    return;
  }
  b -= 8192;

  const float* src = nullptr;  // U matrix (k-major: U[k][n], ld=1024)
  u16* dst = nullptr;          // BT (n-major, ld = Kd)
  int nb = 0, kb = 0, kkb = 0, nnb = 0, Kd = 0;
  if (b < 1024) {                       // B1T: 2048n x 2048k, 32x32 tiles
    const int tn = b & 31, tk = b >> 5;
    src = (tn < 16) ? ((tk < 16) ? Uzl : Uzr) : ((tk < 16) ? Url : Urr);
    nb = tn * 64; kb = tk * 64; nnb = (tn & 15) * 64; kkb = (tk & 15) * 64;
    dst = B1T; Kd = 2048;
  } else if (b < 1536) {                // B2T: 1024n x 2048k, 16x32 tiles
    const int q = b - 1024, tn = q & 15, tk = q >> 4;
    src = (tk < 16) ? Uhl : Uhr;
    nb = tn * 64; kb = tk * 64; nnb = tn * 64; kkb = (tk & 15) * 64;
    dst = B2T; Kd = 2048;
  } else if (b < 1792) {                // BLT: 2048n x 512k, 32x8 tiles
    const int q = b - 1536, tn = q & 31, tk = q >> 5;
    src = (tn < 16) ? Wz : Wh;
    nb = tn * 64; kb = tk * 64; nnb = (tn & 15) * 64; kkb = tk * 64;
    dst = BLT; Kd = 512;
  } else {                              // biases: 4 blocks x 256 = 1024
    const int t = (b - 1792) * 256 + tid;
    bz[t] = bz0[t] + bz1[t] + bz2[t];
    br[t] = br0[t] + br1[t] + br2[t];
    bh[t] = bh0[t] + bh1[t] + bh2[t];
    return;
  }

  // read 64x64 f32 tile coalesced (rows of U), store transposed in LDS
  {
    const int c = tid & 63;            // n-local
    const int r0 = tid >> 6;           // k-local base (4 rows/iter)
    #pragma unroll
    for (int it = 0; it < 16; ++it) {
      const int r = it * 4 + r0;
      sT[c][r] = src[(size_t)(kkb + r) * 1024 + nnb + c];
    }
  }
  __syncthreads();
  // write 64x64 bf16 tile coalesced (rows of BT)
  #pragma unroll
  for (int it = 0; it < 2; ++it) {
    const int idx = it * 256 + tid;
    const int nl = idx >> 3;
    const int kc = (idx & 7) * 8;
    short8 v;
    #pragma unroll
    for (int r = 0; r < 8; ++r) v[r] = (short)f2bf(sT[nl][kc + r]);
    *(short8*)(dst + (size_t)(nb + nl) * Kd + kb + kc) = v;
  }
}

extern "C" void kernel_launch(void* const* d_in, const int* in_sizes, int n_in,
                              void* d_out, int out_size, void* d_ws, size_t ws_size,
                              hipStream_t stream)
{
  const int*   tokens = (const int*)d_in[0];
  const float* emb  = (const float*)d_in[1];
  const float* W_z  = (const float*)d_in[2];
  const float* b_z  = (const float*)d_in[3];
  const float* U_zl = (const float*)d_in[4];
  const float* b_zl = (const float*)d_in[5];
  const float* U_zr = (const float*)d_in[6];
  const float* b_zr = (const float*)d_in[7];
  // d_in[8] = W_r: provably unused (leaf r multiplies zero state)
  const float* b_r  = (const float*)d_in[9];
  const float* U_rl = (const float*)d_in[10];
  const float* b_rl = (const float*)d_in[11];
  const float* U_rr = (const float*)d_in[12];
  const float* b_rr = (const float*)d_in[13];
  const float* W_h  = (const float*)d_in[14];
  const float* b_h  = (const float*)d_in[15];
  const float* U_hl = (const float*)d_in[16];
  const float* b_hl = (const float*)d_in[17];
  const float* U_hr = (const float*)d_in[18];
  const float* b_hr = (const float*)d_in[19];

  char* ws = (char*)d_ws;
  size_t off = 0;
  auto alloc = [&](size_t bytes) -> char* {
    char* p = ws + off; off += (bytes + 255) & ~(size_t)255; return p;
  };
  u16*   B1T  = (u16*)alloc((size_t)2048 * 2048 * 2);   //  8 MB
  u16*   B2T  = (u16*)alloc((size_t)1024 * 2048 * 2);   //  4 MB
  u16*   BLT  = (u16*)alloc((size_t)2048 * 512 * 2);    //  2 MB
  float* bz   = (float*)alloc(1024 * 4);
  float* br   = (float*)alloc(1024 * 4);
  float* bh   = (float*)alloc(1024 * 4);
  u16*   wrd  = (u16*)alloc((size_t)32768 * 512 * 2);   // 32 MB (dead after leaf -> pbuf)
  u16*   hA   = (u16*)alloc((size_t)32768 * 1024 * 2);  // 64 MB
  u16*   hB   = (u16*)alloc((size_t)16384 * 1024 * 2);  // 32 MB
  u16*   zbuf = (u16*)alloc((size_t)16384 * 1024 * 2);  // 32 MB
  u16*   rlrr = (u16*)alloc((size_t)16384 * 2048 * 2);  // 64 MB
  u16*   pbuf = wrd;                                    // aliases wrd (max 32 MB bf16)
  (void)ws_size; (void)in_sizes; (void)n_in; (void)out_size;

  prep_all<<<dim3(8192 + 1024 + 512 + 256 + 4), dim3(256), 0, stream>>>(
      tokens, emb,
      U_zl, U_zr, U_rl, U_rr, U_hl, U_hr, W_z, W_h,
      b_z, b_zl, b_zr, b_r, b_rl, b_rr, b_h, b_hl, b_hr,
      wrd, B1T, B2T, BLT, bz, br, bh);

  leaf_fused<<<dim3(8 * 256), dim3(256), 0, stream>>>(wrd, BLT, bz, bh, hA);

  // 9 halving levels; h (2R x 1024) viewed as (R x 2048) = [hl|hr]
  const u16* hin = hA;
  u16* hout = hB;
  int nodes = 32768;
  for (int lvl = 0; lvl < 9; ++lvl) {
    const int R = nodes >> 1;
    float* outf = (lvl == 8) ? (float*)d_out : nullptr;
    if (lvl < 3) {
      const int NY = (R + 127) / 128;
      gemm_fused<<<dim3(16 * NY), dim3(256), 0, stream>>>(
          hin, B1T, R, 2048, 16, NY, MODE_ZR,
          bz, br, bh, hin, nullptr, zbuf, rlrr, nullptr);
      gemm_fused<<<dim3(8 * NY), dim3(256), 0, stream>>>(
          rlrr, B2T, R, 2048, 8, NY, MODE_OUT,
          bz, br, bh, hin, zbuf, hout, nullptr, outf);
    } else {
      const int TY = (R + 127) / 128;
      const int Mr = TY * 128;
      // S tuned so pk is 1-8 K-iters at >=512 blocks; pbuf = S*Mr*2048*2 <= 32 MB
      const int S  = (R >= 2048) ? 4 : (R >= 1024) ? 8 : (R >= 512) ? 16 : 32;
      gemm_pk<<<dim3(16 * TY * S), dim3(256), 0, stream>>>(
          hin, B1T, 2048, 16, S, Mr, pbuf);
      reduce_zr<<<dim3(R * 2), dim3(256), 0, stream>>>(
          pbuf, R, Mr, S, bz, br, hin, zbuf, rlrr);
      gemm_pk<<<dim3(8 * TY * S), dim3(256), 0, stream>>>(
          rlrr, B2T, 2048, 8, S, Mr, pbuf);
      reduce_out<<<dim3(R), dim3(256), 0, stream>>>(
          pbuf, R, Mr, S, bh, hin, zbuf, hout, outf);
    }
    u16* tmp = (u16*)hin; hin = hout; hout = tmp;
    nodes = R;
  }
}

// Round 13
// 1130.468 us; speedup vs baseline: 1.0756x; 1.0756x over previous
//
#include <hip/hip_runtime.h>
#include <hip/hip_bf16.h>
#include <math.h>

typedef unsigned short u16;
typedef __attribute__((ext_vector_type(8))) short short8;
typedef __attribute__((ext_vector_type(4))) short short4v;
typedef __attribute__((ext_vector_type(4))) float floatx4;

__device__ __forceinline__ float bf2f(u16 u) {
  union { float f; unsigned u; } v; v.u = ((unsigned)u) << 16; return v.f;
}
__device__ __forceinline__ u16 f2bf(float f) {
  union { float f; unsigned u; } v; v.f = f;
  unsigned r = (v.u + 0x7FFFu + ((v.u >> 16) & 1u)) >> 16;
  return (u16)r;
}
__device__ __forceinline__ float sigm(float x) {
  return __builtin_amdgcn_rcpf(1.0f + __expf(-x));
}
__device__ __forceinline__ float ftanh(float x) {
  return 1.0f - 2.0f * __builtin_amdgcn_rcpf(1.0f + __expf(2.0f * x));
}

// async global->LDS, 16B/lane; LDS dest = wave-uniform base + lane*16
__device__ __forceinline__ void ld_g2l16(const u16* g, u16* l) {
  __builtin_amdgcn_global_load_lds(
      (const __attribute__((address_space(1))) void*)g,
      (__attribute__((address_space(3))) void*)l, 16, 0, 0);
}

// R4/R7-measured-best grid order: per XCD, by fastest within a disjoint strip.
__device__ __forceinline__ void swz(int blk, int NX, int NY, int& bx, int& by) {
  if ((NY & 7) == 0) {
    const int strip = NY >> 3;
    const int xcd = blk & 7;
    const int q = blk >> 3;
    bx = q / strip;
    by = xcd * strip + (q - bx * strip);
  } else {
    bx = blk % NX;
    by = blk / NX;
  }
}

#define BM 128
#define BN 128
#define BK 64    // 32 K-iters at K=2048: fewest barrier drains (R5-vs-R6 measured win)
                 // LDS row = 128B = 8x16B chunks; XOR chunk^(row&7) -> conflict-free (R5: 0)

#define MODE_ZR   1
#define MODE_OUT  2

// ---------------- Leaf: h = (1 - sigm(word@Wz + bz)) * tanh(word@Wh + bh)
__global__ __launch_bounds__(256) void leaf_fused(
    const u16* __restrict__ word, const u16* __restrict__ BLT,
    const float* __restrict__ bz, const float* __restrict__ bh,
    u16* __restrict__ hout)   // 32768 x 1024 bf16
{
  __shared__ u16 sA [BM * BK];
  __shared__ u16 sBz[BN * BK];
  __shared__ u16 sBh[BN * BK];
  const int tid  = threadIdx.x;
  int bx, by; swz(blockIdx.x, 8, 256, bx, by);
  const int m0   = by * BM;
  const int n0   = bx * BN;
  const int lane = tid & 63;
  const int wave = tid >> 6;
  const int wm   = (wave >> 1) * 64;
  const int wn   = (wave & 1) * 64;
  const int lr   = lane & 15;
  const int q4   = lane >> 4;
  const int qd   = q4 * 4;
  const int xs   = lr & 7;
  const int srow = lane >> 3;
  const int sc   = lane & 7;
  const int goff = (sc ^ srow) * 8;

  const u16* aP [4]; const u16* bzP[4]; const u16* bhP[4];
  #pragma unroll
  for (int t = 0; t < 4; ++t) {
    const int row = (wave * 4 + t) * 8 + srow;
    aP [t] = word + (size_t)(m0 + row) * 512 + goff;
    bzP[t] = BLT  + (size_t)(n0 + row) * 512 + goff;
    bhP[t] = BLT  + (size_t)(1024 + n0 + row) * 512 + goff;
  }

  floatx4 accz[4][4], acch[4][4];
  #pragma unroll
  for (int j = 0; j < 4; ++j)
    #pragma unroll
    for (int i = 0; i < 4; ++i) {
      accz[j][i] = (floatx4){0.f, 0.f, 0.f, 0.f};
      acch[j][i] = (floatx4){0.f, 0.f, 0.f, 0.f};
    }

  for (int kt = 0; kt < 512 / BK; ++kt) {
    #pragma unroll
    for (int t = 0; t < 4; ++t) {
      const int slab = wave * 4 + t;
      ld_g2l16(aP [t], &sA [slab * 512]);
      ld_g2l16(bzP[t], &sBz[slab * 512]);
      ld_g2l16(bhP[t], &sBh[slab * 512]);
      aP[t] += BK; bzP[t] += BK; bhP[t] += BK;
    }
    __syncthreads();
    #pragma unroll
    for (int s = 0; s < 2; ++s) {
      const int ck = ((s * 4 + q4) ^ xs) * 8;
      short8 af[4], bz8[4], bh8[4];
      #pragma unroll
      for (int i = 0; i < 4; ++i)
        af[i] = *(const short8*)(&sA[(wm + i * 16 + lr) * BK + ck]);
      #pragma unroll
      for (int j = 0; j < 4; ++j) {
        bz8[j] = *(const short8*)(&sBz[(wn + j * 16 + lr) * BK + ck]);
        bh8[j] = *(const short8*)(&sBh[(wn + j * 16 + lr) * BK + ck]);
      }
      #pragma unroll
      for (int j = 0; j < 4; ++j)
        #pragma unroll
        for (int i = 0; i < 4; ++i) {
          accz[j][i] = __builtin_amdgcn_mfma_f32_16x16x32_bf16(bz8[j], af[i], accz[j][i], 0, 0, 0);
          acch[j][i] = __builtin_amdgcn_mfma_f32_16x16x32_bf16(bh8[j], af[i], acch[j][i], 0, 0, 0);
        }
    }
    __syncthreads();
  }

  #pragma unroll
  for (int j = 0; j < 4; ++j) {
    const int cb = n0 + wn + j * 16 + qd;
    const float4 bz4 = *(const float4*)(bz + cb);
    const float4 bh4 = *(const float4*)(bh + cb);
    #pragma unroll
    for (int i = 0; i < 4; ++i) {
      const int grow = m0 + wm + i * 16 + lr;
      short4v o;
      #pragma unroll
      for (int r = 0; r < 4; ++r) {
        const float z  = sigm(accz[j][i][r] + ((const float*)&bz4)[r]);
        const float ht = ftanh(acch[j][i][r] + ((const float*)&bh4)[r]);
        o[r] = (short)f2bf((1.f - z) * ht);
      }
      *(short4v*)(hout + (size_t)grow * 1024 + cb) = o;
    }
  }
}

// ---------------- Big-level GEMM (levels 0-2): C = A @ BT^T, fused epilogues.
__global__ __launch_bounds__(256) void gemm_fused(
    const u16* __restrict__ A, const u16* __restrict__ BT,
    int M, int K, int NX, int NY, int mode,
    const float* __restrict__ bias_z, const float* __restrict__ bias_r,
    const float* __restrict__ bias_h,
    const u16* __restrict__ hin2, const u16* __restrict__ zin,
    u16* __restrict__ out0, u16* __restrict__ out1, float* __restrict__ outf)
{
  __shared__ u16 sA[BM * BK];
  __shared__ u16 sB[BN * BK];
  const int tid  = threadIdx.x;
  int bx, by; swz(blockIdx.x, NX, NY, bx, by);
  const int m0   = by * BM;
  const int n0   = bx * BN;
  const int lane = tid & 63;
  const int wave = tid >> 6;
  const int wm   = (wave >> 1) * 64;
  const int wn   = (wave & 1) * 64;
  const int lr   = lane & 15;
  const int q4   = lane >> 4;
  const int qd   = q4 * 4;
  const int xs   = lr & 7;
  const int srow = lane >> 3;
  const int sc   = lane & 7;
  const int goff = (sc ^ srow) * 8;

  const u16* aP[4]; const u16* bP[4];
  #pragma unroll
  for (int t = 0; t < 4; ++t) {
    const int row = (wave * 4 + t) * 8 + srow;
    aP[t] = A  + (size_t)(m0 + row) * K + goff;
    bP[t] = BT + (size_t)(n0 + row) * K + goff;
  }

  floatx4 acc[4][4];
  #pragma unroll
  for (int j = 0; j < 4; ++j)
    #pragma unroll
    for (int i = 0; i < 4; ++i)
      acc[j][i] = (floatx4){0.f, 0.f, 0.f, 0.f};

  const int ksteps = K / BK;
  for (int kt = 0; kt < ksteps; ++kt) {
    #pragma unroll
    for (int t = 0; t < 4; ++t) {
      const int slab = wave * 4 + t;
      ld_g2l16(aP[t], &sA[slab * 512]);
      ld_g2l16(bP[t], &sB[slab * 512]);
      aP[t] += BK; bP[t] += BK;
    }
    __syncthreads();
    #pragma unroll
    for (int s = 0; s < 2; ++s) {
      const int ck = ((s * 4 + q4) ^ xs) * 8;
      short8 af[4], bfr[4];
      #pragma unroll
      for (int i = 0; i < 4; ++i)
        af[i] = *(const short8*)(&sA[(wm + i * 16 + lr) * BK + ck]);
      #pragma unroll
      for (int j = 0; j < 4; ++j)
        bfr[j] = *(const short8*)(&sB[(wn + j * 16 + lr) * BK + ck]);
      #pragma unroll
      for (int j = 0; j < 4; ++j)
        #pragma unroll
        for (int i = 0; i < 4; ++i)
          acc[j][i] = __builtin_amdgcn_mfma_f32_16x16x32_bf16(bfr[j], af[i], acc[j][i], 0, 0, 0);
    }
    __syncthreads();
  }

  #pragma unroll
  for (int j = 0; j < 4; ++j) {
    const int cb = n0 + wn + j * 16 + qd;
    if (mode == MODE_ZR) {
      if (cb < 1024) {
        const float4 b4 = *(const float4*)(bias_z + cb);
        #pragma unroll
        for (int i = 0; i < 4; ++i) {
          const int grow = m0 + wm + i * 16 + lr;
          if (grow >= M) continue;
          short4v o;
          #pragma unroll
          for (int r = 0; r < 4; ++r)
            o[r] = (short)f2bf(sigm(acc[j][i][r] + ((const float*)&b4)[r]));
          *(short4v*)(out0 + (size_t)grow * 1024 + cb) = o;
        }
      } else {
        const int c2 = cb - 1024;
        const float4 b4 = *(const float4*)(bias_r + c2);
        #pragma unroll
        for (int i = 0; i < 4; ++i) {
          const int grow = m0 + wm + i * 16 + lr;
          if (grow >= M) continue;
          const short4v hl4 = *(const short4v*)(hin2 + (size_t)grow * 2048 + c2);
          const short4v hr4 = *(const short4v*)(hin2 + (size_t)grow * 2048 + 1024 + c2);
          short4v ol, orr;
          #pragma unroll
          for (int r = 0; r < 4; ++r) {
            const float rv = sigm(acc[j][i][r] + ((const float*)&b4)[r]);
            ol[r]  = (short)f2bf(rv * bf2f((u16)hl4[r]));
            orr[r] = (short)f2bf(rv * bf2f((u16)hr4[r]));
          }
          *(short4v*)(out1 + (size_t)grow * 2048 + c2)        = ol;
          *(short4v*)(out1 + (size_t)grow * 2048 + 1024 + c2) = orr;
        }
      }
    } else { // MODE_OUT
      const float4 b4 = *(const float4*)(bias_h + cb);
      #pragma unroll
      for (int i = 0; i < 4; ++i) {
        const int grow = m0 + wm + i * 16 + lr;
        if (grow >= M) continue;
        const short4v z4  = *(const short4v*)(zin  + (size_t)grow * 1024 + cb);
        const short4v hl4 = *(const short4v*)(hin2 + (size_t)grow * 2048 + cb);
        const short4v hr4 = *(const short4v*)(hin2 + (size_t)grow * 2048 + 1024 + cb);
        float h[4];
        #pragma unroll
        for (int r = 0; r < 4; ++r) {
          const float ht = ftanh(acc[j][i][r] + ((const float*)&b4)[r]);
          const float z  = bf2f((u16)z4[r]);
          h[r] = z * (bf2f((u16)hl4[r]) + bf2f((u16)hr4[r])) + (1.f - z) * ht;
        }
        if (outf) {
          *(float4*)(outf + (size_t)grow * 1024 + cb) = (float4){h[0], h[1], h[2], h[3]};
        } else {
          short4v o;
          #pragma unroll
          for (int r = 0; r < 4; ++r) o[r] = (short)f2bf(h[r]);
          *(short4v*)(out0 + (size_t)grow * 1024 + cb) = o;
        }
      }
    }
  }
}

// ---------------- Split-K phase 1 (levels 3-8): bf16 partials, plain stores.
__global__ __launch_bounds__(256) void gemm_pk(
    const u16* __restrict__ A, const u16* __restrict__ BT,
    int K, int TX, int S, int Mr,
    u16* __restrict__ pbuf)
{
  __shared__ u16 sA[BM * BK];
  __shared__ u16 sB[BN * BK];
  const int tid  = threadIdx.x;
  const int blk  = blockIdx.x;
  const int sp   = blk % S;
  const int tile = blk / S;
  const int bx   = tile % TX;
  const int by   = tile / TX;
  const int N    = TX * 128;
  const int m0   = by * BM;
  const int n0   = bx * BN;
  const int k0   = sp * (K / S);
  const int lane = tid & 63;
  const int wave = tid >> 6;
  const int wm   = (wave >> 1) * 64;
  const int wn   = (wave & 1) * 64;
  const int lr   = lane & 15;
  const int q4   = lane >> 4;
  const int qd   = q4 * 4;
  const int xs   = lr & 7;
  const int srow = lane >> 3;
  const int sc   = lane & 7;
  const int goff = (sc ^ srow) * 8;

  const u16* aP[4]; const u16* bP[4];
  #pragma unroll
  for (int t = 0; t < 4; ++t) {
    const int row = (wave * 4 + t) * 8 + srow;
    aP[t] = A  + (size_t)(m0 + row) * K + k0 + goff;  // OOB rows: in-ws garbage, masked in reduce
    bP[t] = BT + (size_t)(n0 + row) * K + k0 + goff;
  }

  floatx4 acc[4][4];
  #pragma unroll
  for (int j = 0; j < 4; ++j)
    #pragma unroll
    for (int i = 0; i < 4; ++i)
      acc[j][i] = (floatx4){0.f, 0.f, 0.f, 0.f};

  const int ksteps = (K / S) / BK;
  for (int kt = 0; kt < ksteps; ++kt) {
    #pragma unroll
    for (int t = 0; t < 4; ++t) {
      const int slab = wave * 4 + t;
      ld_g2l16(aP[t], &sA[slab * 512]);
      ld_g2l16(bP[t], &sB[slab * 512]);
      aP[t] += BK; bP[t] += BK;
    }
    __syncthreads();
    #pragma unroll
    for (int s = 0; s < 2; ++s) {
      const int ck = ((s * 4 + q4) ^ xs) * 8;
      short8 af[4], bfr[4];
      #pragma unroll
      for (int i = 0; i < 4; ++i)
        af[i] = *(const short8*)(&sA[(wm + i * 16 + lr) * BK + ck]);
      #pragma unroll
      for (int j = 0; j < 4; ++j)
        bfr[j] = *(const short8*)(&sB[(wn + j * 16 + lr) * BK + ck]);
      #pragma unroll
      for (int j = 0; j < 4; ++j)
        #pragma unroll
        for (int i = 0; i < 4; ++i)
          acc[j][i] = __builtin_amdgcn_mfma_f32_16x16x32_bf16(bfr[j], af[i], acc[j][i], 0, 0, 0);
    }
    __syncthreads();
  }

  u16* base = pbuf + (size_t)sp * Mr * N;
  #pragma unroll
  for (int j = 0; j < 4; ++j) {
    const int cb = n0 + wn + j * 16 + qd;
    #pragma unroll
    for (int i = 0; i < 4; ++i) {
      const int grow = m0 + wm + i * 16 + lr;
      short4v o;
      #pragma unroll
      for (int r = 0; r < 4; ++r) o[r] = (short)f2bf(acc[j][i][r]);
      *(short4v*)(base + (size_t)grow * N + cb) = o;
    }
  }
}

// ---------------- Split-K phase 2: sum S bf16 slices + ZR epilogue (N=2048)
__global__ __launch_bounds__(256) void reduce_zr(
    const u16* __restrict__ pbuf, int M, int Mr, int S,
    const float* __restrict__ bias_z, const float* __restrict__ bias_r,
    const u16* __restrict__ hin2,
    u16* __restrict__ out0, u16* __restrict__ out1)
{
  const int t = blockIdx.x * 256 + threadIdx.x;
  const int grow = t >> 9;
  const int cb = (t & 511) * 4;
  if (grow >= M) return;
  float v[4] = {0.f, 0.f, 0.f, 0.f};
  for (int s = 0; s < S; ++s) {
    const short4v p = *(const short4v*)(pbuf + ((size_t)s * Mr + grow) * 2048 + cb);
    #pragma unroll
    for (int r = 0; r < 4; ++r) v[r] += bf2f((u16)p[r]);
  }
  if (cb < 1024) {
    short4v o;
    #pragma unroll
    for (int r = 0; r < 4; ++r)
      o[r] = (short)f2bf(sigm(v[r] + bias_z[cb + r]));
    *(short4v*)(out0 + (size_t)grow * 1024 + cb) = o;
  } else {
    const int c2 = cb - 1024;
    const short4v hl4 = *(const short4v*)(hin2 + (size_t)grow * 2048 + c2);
    const short4v hr4 = *(const short4v*)(hin2 + (size_t)grow * 2048 + 1024 + c2);
    short4v ol, orr;
    #pragma unroll
    for (int r = 0; r < 4; ++r) {
      const float rv = sigm(v[r] + bias_r[c2 + r]);
      ol[r]  = (short)f2bf(rv * bf2f((u16)hl4[r]));
      orr[r] = (short)f2bf(rv * bf2f((u16)hr4[r]));
    }
    *(short4v*)(out1 + (size_t)grow * 2048 + c2)        = ol;
    *(short4v*)(out1 + (size_t)grow * 2048 + 1024 + c2) = orr;
  }
}

// ---------------- Split-K phase 2: sum S bf16 slices + OUT epilogue (N=1024)
__global__ __launch_bounds__(256) void reduce_out(
    const u16* __restrict__ pbuf, int M, int Mr, int S,
    const float* __restrict__ bias_h,
    const u16* __restrict__ hin2, const u16* __restrict__ zin,
    u16* __restrict__ out0, float* __restrict__ outf)
{
  const int t = blockIdx.x * 256 + threadIdx.x;
  const int grow = t >> 8;
  const int cb = (t & 255) * 4;
  if (grow >= M) return;
  float v[4] = {0.f, 0.f, 0.f, 0.f};
  for (int s = 0; s < S; ++s) {
    const short4v p = *(const short4v*)(pbuf + ((size_t)s * Mr + grow) * 1024 + cb);
    #pragma unroll
    for (int r = 0; r < 4; ++r) v[r] += bf2f((u16)p[r]);
  }
  const short4v z4  = *(const short4v*)(zin  + (size_t)grow * 1024 + cb);
  const short4v hl4 = *(const short4v*)(hin2 + (size_t)grow * 2048 + cb);
  const short4v hr4 = *(const short4v*)(hin2 + (size_t)grow * 2048 + 1024 + cb);
  float h[4];
  #pragma unroll
  for (int r = 0; r < 4; ++r) {
    const float ht = ftanh(v[r] + bias_h[cb + r]);
    const float z  = bf2f((u16)z4[r]);
    h[r] = z * (bf2f((u16)hl4[r]) + bf2f((u16)hr4[r])) + (1.f - z) * ht;
  }
  if (outf) {
    *(float4*)(outf + (size_t)grow * 1024 + cb) = (float4){h[0], h[1], h[2], h[3]};
  } else {
    short4v o;
    #pragma unroll
    for (int r = 0; r < 4; ++r) o[r] = (short)f2bf(h[r]);
    *(short4v*)(out0 + (size_t)grow * 1024 + cb) = o;
  }
}

// ---------------- prep mega-kernel: token gather + LDS-transposed weight packs
__global__ __launch_bounds__(256) void prep_all(
    const int* __restrict__ tokens, const float* __restrict__ emb,
    const float* __restrict__ Uzl, const float* __restrict__ Uzr,
    const float* __restrict__ Url, const float* __restrict__ Urr,
    const float* __restrict__ Uhl, const float* __restrict__ Uhr,
    const float* __restrict__ Wz,  const float* __restrict__ Wh,
    const float* bz0, const float* bz1, const float* bz2,
    const float* br0, const float* br1, const float* br2,
    const float* bh0, const float* bh1, const float* bh2,
    u16* __restrict__ word,
    u16* __restrict__ B1T, u16* __restrict__ B2T, u16* __restrict__ BLT,
    float* __restrict__ bz, float* __restrict__ br, float* __restrict__ bh)
{
  __shared__ float sT[64][65];
  const int tid = threadIdx.x;
  int b = blockIdx.x;

  if (b < 8192) {                       // token gather (f32 -> bf16)
    const int t = b * 256 + tid;
    const int row = t >> 6;
    const int col = (t & 63) * 8;
    const float* src = emb + (size_t)tokens[row] * 512 + col;
    float4 a = *(const float4*)src;
    float4 c = *(const float4*)(src + 4);
    short8 v;
    v[0] = (short)f2bf(a.x); v[1] = (short)f2bf(a.y);
    v[2] = (short)f2bf(a.z); v[3] = (short)f2bf(a.w);
    v[4] = (short)f2bf(c.x); v[5] = (short)f2bf(c.y);
    v[6] = (short)f2bf(c.z); v[7] = (short)f2bf(c.w);
    *(short8*)(word + (size_t)row * 512 + col) = v;
    return;
  }
  b -= 8192;

  const float* src = nullptr;  // U matrix (k-major: U[k][n], ld=1024)
  u16* dst = nullptr;          // BT (n-major, ld = Kd)
  int nb = 0, kb = 0, kkb = 0, nnb = 0, Kd = 0;
  if (b < 1024) {                       // B1T: 2048n x 2048k, 32x32 tiles
    const int tn = b & 31, tk = b >> 5;
    src = (tn < 16) ? ((tk < 16) ? Uzl : Uzr) : ((tk < 16) ? Url : Urr);
    nb = tn * 64; kb = tk * 64; nnb = (tn & 15) * 64; kkb = (tk & 15) * 64;
    dst = B1T; Kd = 2048;
  } else if (b < 1536) {                // B2T: 1024n x 2048k, 16x32 tiles
    const int q = b - 1024, tn = q & 15, tk = q >> 4;
    src = (tk < 16) ? Uhl : Uhr;
    nb = tn * 64; kb = tk * 64; nnb = tn * 64; kkb = (tk & 15) * 64;
    dst = B2T; Kd = 2048;
  } else if (b < 1792) {                // BLT: 2048n x 512k, 32x8 tiles
    const int q = b - 1536, tn = q & 31, tk = q >> 5;
    src = (tn < 16) ? Wz : Wh;
    nb = tn * 64; kb = tk * 64; nnb = (tn & 15) * 64; kkb = tk * 64;
    dst = BLT; Kd = 512;
  } else {                              // biases: 4 blocks x 256 = 1024
    const int t = (b - 1792) * 256 + tid;
    bz[t] = bz0[t] + bz1[t] + bz2[t];
    br[t] = br0[t] + br1[t] + br2[t];
    bh[t] = bh0[t] + bh1[t] + bh2[t];
    return;
  }

  // read 64x64 f32 tile coalesced (rows of U), store transposed in LDS
  {
    const int c = tid & 63;            // n-local
    const int r0 = tid >> 6;           // k-local base (4 rows/iter)
    #pragma unroll
    for (int it = 0; it < 16; ++it) {
      const int r = it * 4 + r0;
      sT[c][r] = src[(size_t)(kkb + r) * 1024 + nnb + c];
    }
  }
  __syncthreads();
  // write 64x64 bf16 tile coalesced (rows of BT)
  #pragma unroll
  for (int it = 0; it < 2; ++it) {
    const int idx = it * 256 + tid;
    const int nl = idx >> 3;
    const int kc = (idx & 7) * 8;
    short8 v;
    #pragma unroll
    for (int r = 0; r < 8; ++r) v[r] = (short)f2bf(sT[nl][kc + r]);
    *(short8*)(dst + (size_t)(nb + nl) * Kd + kb + kc) = v;
  }
}

extern "C" void kernel_launch(void* const* d_in, const int* in_sizes, int n_in,
                              void* d_out, int out_size, void* d_ws, size_t ws_size,
                              hipStream_t stream)
{
  const int*   tokens = (const int*)d_in[0];
  const float* emb  = (const float*)d_in[1];
  const float* W_z  = (const float*)d_in[2];
  const float* b_z  = (const float*)d_in[3];
  const float* U_zl = (const float*)d_in[4];
  const float* b_zl = (const float*)d_in[5];
  const float* U_zr = (const float*)d_in[6];
  const float* b_zr = (const float*)d_in[7];
  // d_in[8] = W_r: provably unused (leaf r multiplies zero state)
  const float* b_r  = (const float*)d_in[9];
  const float* U_rl = (const float*)d_in[10];
  const float* b_rl = (const float*)d_in[11];
  const float* U_rr = (const float*)d_in[12];
  const float* b_rr = (const float*)d_in[13];
  const float* W_h  = (const float*)d_in[14];
  const float* b_h  = (const float*)d_in[15];
  const float* U_hl = (const float*)d_in[16];
  const float* b_hl = (const float*)d_in[17];
  const float* U_hr = (const float*)d_in[18];
  const float* b_hr = (const float*)d_in[19];

  char* ws = (char*)d_ws;
  size_t off = 0;
  auto alloc = [&](size_t bytes) -> char* {
    char* p = ws + off; off += (bytes + 255) & ~(size_t)255; return p;
  };
  u16*   B1T  = (u16*)alloc((size_t)2048 * 2048 * 2);   //  8 MB
  u16*   B2T  = (u16*)alloc((size_t)1024 * 2048 * 2);   //  4 MB
  u16*   BLT  = (u16*)alloc((size_t)2048 * 512 * 2);    //  2 MB
  float* bz   = (float*)alloc(1024 * 4);
  float* br   = (float*)alloc(1024 * 4);
  float* bh   = (float*)alloc(1024 * 4);
  u16*   wrd  = (u16*)alloc((size_t)32768 * 512 * 2);   // 32 MB (dead after leaf -> pbuf)
  u16*   hA   = (u16*)alloc((size_t)32768 * 1024 * 2);  // 64 MB
  u16*   hB   = (u16*)alloc((size_t)16384 * 1024 * 2);  // 32 MB
  u16*   zbuf = (u16*)alloc((size_t)16384 * 1024 * 2);  // 32 MB
  u16*   rlrr = (u16*)alloc((size_t)16384 * 2048 * 2);  // 64 MB
  u16*   pbuf = wrd;                                    // aliases wrd (max 32 MB bf16)
  (void)ws_size; (void)in_sizes; (void)n_in; (void)out_size;

  prep_all<<<dim3(8192 + 1024 + 512 + 256 + 4), dim3(256), 0, stream>>>(
      tokens, emb,
      U_zl, U_zr, U_rl, U_rr, U_hl, U_hr, W_z, W_h,
      b_z, b_zl, b_zr, b_r, b_rl, b_rr, b_h, b_hl, b_hr,
      wrd, B1T, B2T, BLT, bz, br, bh);

  leaf_fused<<<dim3(8 * 256), dim3(256), 0, stream>>>(wrd, BLT, bz, bh, hA);

  // 9 halving levels; h (2R x 1024) viewed as (R x 2048) = [hl|hr]
  const u16* hin = hA;
  u16* hout = hB;
  int nodes = 32768;
  for (int lvl = 0; lvl < 9; ++lvl) {
    const int R = nodes >> 1;
    float* outf = (lvl == 8) ? (float*)d_out : nullptr;
    if (lvl < 3) {
      const int NY = (R + 127) / 128;
      gemm_fused<<<dim3(16 * NY), dim3(256), 0, stream>>>(
          hin, B1T, R, 2048, 16, NY, MODE_ZR,
          bz, br, bh, hin, nullptr, zbuf, rlrr, nullptr);
      gemm_fused<<<dim3(8 * NY), dim3(256), 0, stream>>>(
          rlrr, B2T, R, 2048, 8, NY, MODE_OUT,
          bz, br, bh, hin, zbuf, hout, nullptr, outf);
    } else {
      const int TY = (R + 127) / 128;
      const int Mr = TY * 128;
      // R11-measured-best S schedule (R12's larger S regressed +18 us)
      const int S  = (R >= 1024) ? 4 : (R >= 256) ? 8 : 16;
      gemm_pk<<<dim3(16 * TY * S), dim3(256), 0, stream>>>(
          hin, B1T, 2048, 16, S, Mr, pbuf);
      reduce_zr<<<dim3(R * 2), dim3(256), 0, stream>>>(
          pbuf, R, Mr, S, bz, br, hin, zbuf, rlrr);
      gemm_pk<<<dim3(8 * TY * S), dim3(256), 0, stream>>>(
          rlrr, B2T, 2048, 8, S, Mr, pbuf);
      reduce_out<<<dim3(R), dim3(256), 0, stream>>>(
          pbuf, R, Mr, S, bh, hin, zbuf, hout, outf);
    }
    u16* tmp = (u16*)hin; hin = hout; hout = tmp;
    nodes = R;
  }
}